// Round 7
// baseline (3239.909 us; speedup 1.0000x reference)
//
#include <hip/hip_runtime.h>
#include <hip/hip_bf16.h>

typedef __hip_bfloat16 bf16;
typedef __attribute__((ext_vector_type(8))) short short8;
typedef __attribute__((ext_vector_type(4))) float f32x4;

#define B_SZ 2
#define L_SEQ 512
#define VOCAB 512
#define D_MODEL 768
#define N_LAYERS 12
#define D_STATE 16
#define D_CONV 4
#define D_INNER 1536
#define DT_RANK 48
#define M_ROWS 1024
#define XDBL_C 80

// scan geometry: 8 d-lanes x 32 chunks of 16 steps
#define SDG 8
#define SNCH 32
#define SCL 16

// gemm tile
#define TBM 128
#define TBN 128
#define TBK 32

__device__ __forceinline__ float silu_f(float x) {
    return x / (1.f + expf(-x));
}

__device__ __forceinline__ float b2f(bf16 x) { return __bfloat162float(x); }

__device__ __forceinline__ float bs2f(short s) {
    union { unsigned int u; float f; } cv;
    cv.u = ((unsigned int)(unsigned short)s) << 16;
    return cv.f;
}

__device__ __forceinline__ short f2bs(float x) {
    bf16 t = __float2bfloat16(x);
    return *reinterpret_cast<short*>(&t);
}

// fp32 -> bf16 bulk convert, 8 elems/thread
__global__ __launch_bounds__(256) void to_bf16_kernel(
    const float* __restrict__ src, bf16* __restrict__ dst, int n8)
{
    int i = blockIdx.x * 256 + threadIdx.x;
    if (i >= n8) return;
    const float4* s = (const float4*)src + (size_t)i * 2;
    float4 a = s[0], b = s[1];
    short8 v;
    v[0] = f2bs(a.x); v[1] = f2bs(a.y); v[2] = f2bs(a.z); v[3] = f2bs(a.w);
    v[4] = f2bs(b.x); v[5] = f2bs(b.y); v[6] = f2bs(b.z); v[7] = f2bs(b.w);
    *(short8*)((short*)dst + (size_t)i * 8) = v;
}

// C[M,N] = A[M,K(lda)] * W[N,K(ldw)]^T (+bias) (+addsrc) (act 1 = softplus)
// A, W bf16. Outputs optional: Cf fp32, Cb bf16. 128x128x32 tile, 4 waves.
__global__ __launch_bounds__(256) void gemm_bf16(
    const bf16* __restrict__ A, int lda,
    const bf16* __restrict__ W, int ldw,
    const float* __restrict__ bias, const float* addsrc,
    float* Cf, bf16* Cb, int M, int N, int K, int act)
{
    __shared__ short As[TBM * TBK];
    __shared__ short Ws[TBN * TBK];
    int t = threadIdx.x;
    int m0 = blockIdx.y * TBM, n0 = blockIdx.x * TBN;
    int wave = t >> 6, lane = t & 63;
    int wr = wave >> 1, wc = wave & 1;       // 2x2 waves, each 64x64
    int lrow = lane & 15, lk = lane >> 4;
    int srow = t >> 2, scol = (t & 3) * 8;

    f32x4 acc[4][4] = {};

    for (int k0 = 0; k0 < K; k0 += TBK) {
        int gk = k0 + scol;
#pragma unroll
        for (int p = 0; p < 2; p++) {
            int r = srow + p * 64;
            short8 v = {};
            if (gk < K) v = *(const short8*)(A + (size_t)(m0 + r) * lda + gk);
            *(short8*)(&As[r * TBK + scol]) = v;
        }
#pragma unroll
        for (int p = 0; p < 2; p++) {
            int r = srow + p * 64;
            int gn = n0 + r;
            short8 v = {};
            if (gn < N && gk < K) v = *(const short8*)(W + (size_t)gn * ldw + gk);
            *(short8*)(&Ws[r * TBK + scol]) = v;
        }
        __syncthreads();

        short8 af[4], bw[4];
#pragma unroll
        for (int i = 0; i < 4; i++) {
            af[i] = *(const short8*)(&As[(wr * 64 + i * 16 + lrow) * TBK + lk * 8]);
            bw[i] = *(const short8*)(&Ws[(wc * 64 + i * 16 + lrow) * TBK + lk * 8]);
        }
#pragma unroll
        for (int i = 0; i < 4; i++)
#pragma unroll
            for (int j = 0; j < 4; j++)
                acc[i][j] = __builtin_amdgcn_mfma_f32_16x16x32_bf16(af[i], bw[j], acc[i][j], 0, 0, 0);
        __syncthreads();
    }

#pragma unroll
    for (int i = 0; i < 4; i++)
#pragma unroll
        for (int j = 0; j < 4; j++) {
            int col = n0 + wc * 64 + j * 16 + lrow;
            if (col >= N) continue;
#pragma unroll
            for (int r = 0; r < 4; r++) {
                int row = m0 + wr * 64 + i * 16 + lk * 4 + r;
                float v = acc[i][j][r];
                if (bias) v += bias[col];
                if (addsrc) v += addsrc[(size_t)row * N + col];
                if (act == 1) v = (v > 20.f) ? v : log1pf(expf(v));
                if (Cf) Cf[(size_t)row * N + col] = v;
                if (Cb) Cb[(size_t)row * N + col] = __float2bfloat16(v);
            }
        }
}

__global__ __launch_bounds__(256) void embed_kernel(
    const float* __restrict__ emb, const int* __restrict__ ids,
    float* __restrict__ x, bf16* __restrict__ xb)
{
    int idx = blockIdx.x * 256 + threadIdx.x;
    if (idx >= M_ROWS * D_MODEL) return;
    int m = idx / D_MODEL, k = idx % D_MODEL;
    float v = emb[(size_t)ids[m] * D_MODEL + k];
    x[idx] = v;
    xb[idx] = __float2bfloat16(v);
}

// vectorized conv+silu: 8 channels per thread
__global__ __launch_bounds__(256) void conv_silu_kernel(
    const bf16* __restrict__ xr, const float* __restrict__ w,
    const float* __restrict__ bias, bf16* __restrict__ u)
{
    int idx = blockIdx.x * 256 + threadIdx.x;       // over M_ROWS * 192
    if (idx >= M_ROWS * (D_INNER / 8)) return;
    int d8 = idx % (D_INNER / 8), m = idx / (D_INNER / 8);
    int d = d8 * 8;
    int l = m % L_SEQ;
    float acc[8];
#pragma unroll
    for (int q = 0; q < 8; q++) acc[q] = bias[d + q];
#pragma unroll
    for (int j = 0; j < D_CONV; j++) {
        int ls = l - (D_CONV - 1) + j;
        if (ls < 0) continue;
        short8 v = *(const short8*)(xr + (size_t)(m - (D_CONV - 1) + j) * (2 * D_INNER) + d);
#pragma unroll
        for (int q = 0; q < 8; q++)
            acc[q] += w[(d + q) * D_CONV + j] * bs2f(v[q]);
    }
    short8 sv;
#pragma unroll
    for (int q = 0; q < 8; q++) sv[q] = f2bs(silu_f(acc[q]));
    *(short8*)(u + (size_t)m * D_INNER + d) = sv;
}

// Chunked parallel scan, d-per-lane layout (see round 5).
__global__ __launch_bounds__(256) void scan_chunked(
    const bf16* __restrict__ delta, const bf16* __restrict__ u,
    const bf16* __restrict__ xdbl, bf16* xrg,
    const float* __restrict__ A_log, const float* __restrict__ Dp)
{
    int t = threadIdx.x;
    int dl_ = t & (SDG - 1);
    int c   = t >> 3;
    int bg  = blockIdx.x;
    int b   = bg / (D_INNER / SDG);
    int dg  = bg % (D_INNER / SDG);
    int d   = dg * SDG + dl_;

    __shared__ float Pl[SNCH][SDG][17];
    __shared__ float Ql[SNCH][SDG][17];

    float An[D_STATE], h[D_STATE], Pp[D_STATE];
#pragma unroll
    for (int n = 0; n < D_STATE; n++) {
        An[n] = -expf(A_log[d * D_STATE + n]);
        h[n] = 0.f;
        Pp[n] = 1.f;
    }

    int m0 = b * L_SEQ + c * SCL;

    for (int i = 0; i < SCL; i++) {
        size_t m = m0 + i;
        float dlv = b2f(delta[m * D_INNER + d]);
        float uvv = b2f(u[m * D_INNER + d]);
        float duv = dlv * uvv;
        const short8* brow = (const short8*)((const short*)xdbl + m * XDBL_C + DT_RANK);
        short8 b0 = brow[0], b1 = brow[1];
#pragma unroll
        for (int n = 0; n < D_STATE; n++) {
            float a = expf(dlv * An[n]);
            Pp[n] *= a;
            float Bn = bs2f(n < 8 ? b0[n] : b1[n - 8]);
            h[n] = a * h[n] + duv * Bn;
        }
    }
#pragma unroll
    for (int n = 0; n < D_STATE; n++) {
        Pl[c][dl_][n] = Pp[n];
        Ql[c][dl_][n] = h[n];
    }
    __syncthreads();

    if (t < SDG * D_STATE) {
        int dd = t & (SDG - 1);
        int nn = t >> 3;
        float h0 = 0.f;
        for (int cc = 0; cc < SNCH; cc++) {
            float p = Pl[cc][dd][nn];
            float q = Ql[cc][dd][nn];
            Pl[cc][dd][nn] = h0;
            h0 = p * h0 + q;
        }
    }
    __syncthreads();

    float Dv = Dp[d];
#pragma unroll
    for (int n = 0; n < D_STATE; n++) h[n] = Pl[c][dl_][n];
    for (int i = 0; i < SCL; i++) {
        size_t m = m0 + i;
        float dlv = b2f(delta[m * D_INNER + d]);
        float uvv = b2f(u[m * D_INNER + d]);
        float duv = dlv * uvv;
        const short8* brow = (const short8*)((const short*)xdbl + m * XDBL_C + DT_RANK);
        short8 b0 = brow[0], b1 = brow[1];
        short8 c0 = brow[2], c1 = brow[3];
        float y = 0.f;
#pragma unroll
        for (int n = 0; n < D_STATE; n++) {
            float a = expf(dlv * An[n]);
            float Bn = bs2f(n < 8 ? b0[n] : b1[n - 8]);
            float Cn = bs2f(n < 8 ? c0[n] : c1[n - 8]);
            h[n] = a * h[n] + duv * Bn;
            y += h[n] * Cn;
        }
        y += uvv * Dv;
        float r = b2f(xrg[m * (2 * D_INNER) + D_INNER + d]);
        xrg[m * (2 * D_INNER) + d] = __float2bfloat16(y * silu_f(r));
    }
}

__global__ __launch_bounds__(256) void ln_kernel(
    const float* __restrict__ x, const float* __restrict__ gam,
    const float* __restrict__ bet, float* __restrict__ hidden_f32,
    bf16* __restrict__ hidden_bf)
{
    int row = blockIdx.x;
    const float* xr = x + (size_t)row * D_MODEL;
    float s = 0.f, s2 = 0.f;
    for (int i = threadIdx.x; i < D_MODEL; i += 256) {
        float v = xr[i];
        s += v; s2 += v * v;
    }
    __shared__ float red[18];
#pragma unroll
    for (int off = 32; off; off >>= 1) {
        s += __shfl_down(s, off);
        s2 += __shfl_down(s2, off);
    }
    int wid = threadIdx.x / 64, lane = threadIdx.x % 64;
    if (lane == 0) { red[wid * 2] = s; red[wid * 2 + 1] = s2; }
    __syncthreads();
    if (threadIdx.x == 0) {
        float ts = 0.f, ts2 = 0.f;
        for (int w = 0; w < 4; w++) { ts += red[w * 2]; ts2 += red[w * 2 + 1]; }
        red[16] = ts; red[17] = ts2;
    }
    __syncthreads();
    float mean = red[16] / D_MODEL;
    float var = red[17] / D_MODEL - mean * mean;
    float inv = rsqrtf(var + 1e-5f);
    for (int i = threadIdx.x; i < D_MODEL; i += 256) {
        float v = (xr[i] - mean) * inv * gam[i] + bet[i];
        hidden_f32[(size_t)row * D_MODEL + i] = v;
        hidden_bf[(size_t)row * D_MODEL + i] = __float2bfloat16(v);
    }
}

extern "C" void kernel_launch(void* const* d_in, const int* in_sizes, int n_in,
                              void* d_out, int out_size, void* d_ws, size_t ws_size,
                              hipStream_t stream) {
    const float* emb    = (const float*)d_in[0];
    const float* in_w   = (const float*)d_in[1];
    const float* conv_w = (const float*)d_in[2];
    const float* conv_b = (const float*)d_in[3];
    const float* xp_w   = (const float*)d_in[4];
    const float* dt_w   = (const float*)d_in[5];
    const float* dt_b   = (const float*)d_in[6];
    const float* A_log  = (const float*)d_in[7];
    const float* Dp     = (const float*)d_in[8];
    const float* out_w  = (const float*)d_in[9];
    const float* ln_g   = (const float*)d_in[10];
    const float* ln_b   = (const float*)d_in[11];
    const float* head_w = (const float*)d_in[12];
    const float* head_b = (const float*)d_in[13];
    const int*   ids    = (const int*)d_in[14];

    float* out_logits = (float*)d_out;
    float* out_hidden = (float*)d_out + (size_t)M_ROWS * VOCAB;

    char* base = (char*)d_ws;
    float* x       = (float*)(base);                        // 3,145,728 B
    bf16*  xb      = (bf16*) (base + 3145728);              // 1,572,864
    bf16*  xr      = (bf16*) (base + 4718592);              // 6,291,456
    bf16*  R       = (bf16*) (base + 11010048);             // 3,145,728
    bf16*  dlt     = (bf16*) (base + 14155776);             // 3,145,728
    bf16*  xdbl    = (bf16*) (base + 17301504);             //   163,840
    bf16*  hidb    = (bf16*) (base + 17465344);             // 1,572,864
    bf16*  in_wb   = (bf16*) (base + 19038208);             // 56,623,104
    bf16*  xp_wb   = (bf16*) (base + 75661312);             //  2,949,120
    bf16*  dt_wb   = (bf16*) (base + 78610432);             //  1,769,472
    bf16*  out_wb  = (bf16*) (base + 80379904);             // 28,311,552
    bf16*  head_wb = (bf16*) (base + 108691456);            //    786,432

    // weight conversion (per call; ~90 MB)
    {
        struct { const float* s; bf16* d; int n; } cv[5] = {
            { in_w,   in_wb,   N_LAYERS * 2 * D_INNER * D_MODEL },
            { xp_w,   xp_wb,   N_LAYERS * XDBL_C * D_INNER },
            { dt_w,   dt_wb,   N_LAYERS * D_INNER * DT_RANK },
            { out_w,  out_wb,  N_LAYERS * D_MODEL * D_INNER },
            { head_w, head_wb, VOCAB * D_MODEL },
        };
        for (int i = 0; i < 5; i++) {
            int n8 = cv[i].n / 8;
            to_bf16_kernel<<<(n8 + 255) / 256, 256, 0, stream>>>(cv[i].s, cv[i].d, n8);
        }
    }

    embed_kernel<<<(M_ROWS * D_MODEL + 255) / 256, 256, 0, stream>>>(emb, ids, x, xb);

    for (int i = 0; i < N_LAYERS; i++) {
        const bf16*  in_wb_i  = in_wb  + (size_t)i * 2 * D_INNER * D_MODEL;
        const float* conv_w_i = conv_w + (size_t)i * D_INNER * D_CONV;
        const float* conv_b_i = conv_b + (size_t)i * D_INNER;
        const bf16*  xp_wb_i  = xp_wb  + (size_t)i * XDBL_C * D_INNER;
        const bf16*  dt_wb_i  = dt_wb  + (size_t)i * D_INNER * DT_RANK;
        const float* dt_b_i   = dt_b   + (size_t)i * D_INNER;
        const float* A_log_i  = A_log  + (size_t)i * D_INNER * D_STATE;
        const float* Dp_i     = Dp     + (size_t)i * D_INNER;
        const bf16*  out_wb_i = out_wb + (size_t)i * D_MODEL * D_INNER;

        // xr = xb @ in_w^T  [1024, 3072] bf16   (24 n-tiles x 8 m-tiles; n%8==0 -> W strip stays on one XCD)
        gemm_bf16<<<dim3(2 * D_INNER / TBN, M_ROWS / TBM), 256, 0, stream>>>(
            xb, D_MODEL, in_wb_i, D_MODEL, nullptr, nullptr, nullptr, xr,
            M_ROWS, 2 * D_INNER, D_MODEL, 0);

        // R = u = silu(conv(xr[:, :1536]) + conv_b)
        conv_silu_kernel<<<(M_ROWS * (D_INNER / 8) + 255) / 256, 256, 0, stream>>>(
            xr, conv_w_i, conv_b_i, R);

        // xdbl = R @ xp_w^T  [1024, 80]
        gemm_bf16<<<dim3(1, M_ROWS / TBM), 256, 0, stream>>>(
            R, D_INNER, xp_wb_i, D_INNER, nullptr, nullptr, nullptr, xdbl,
            M_ROWS, XDBL_C, D_INNER, 0);

        // dlt = softplus(xdbl[:, :48] @ dt_w^T + dt_b)  [1024, 1536]
        gemm_bf16<<<dim3(D_INNER / TBN, M_ROWS / TBM), 256, 0, stream>>>(
            xdbl, XDBL_C, dt_wb_i, DT_RANK, dt_b_i, nullptr, nullptr, dlt,
            M_ROWS, D_INNER, DT_RANK, 1);

        // scan + gate fused; g -> xr[:, 0:1536]
        scan_chunked<<<B_SZ * (D_INNER / SDG), 256, 0, stream>>>(
            dlt, R, xdbl, xr, A_log_i, Dp_i);

        // x = g @ out_w^T + x ; also xb = bf16(x)
        gemm_bf16<<<dim3(D_MODEL / TBN, M_ROWS / TBM), 256, 0, stream>>>(
            xr, 2 * D_INNER, out_wb_i, D_INNER, nullptr, x, x, xb,
            M_ROWS, D_MODEL, D_INNER, 0);
    }

    ln_kernel<<<M_ROWS, 256, 0, stream>>>(x, ln_g, ln_b, out_hidden, hidb);

    gemm_bf16<<<dim3(VOCAB / TBN, M_ROWS / TBM), 256, 0, stream>>>(
        hidb, D_MODEL, head_wb, D_MODEL, head_b, nullptr, out_logits, nullptr,
        M_ROWS, VOCAB, D_MODEL, 0);
}

// Round 8
// 2593.319 us; speedup vs baseline: 1.2493x; 1.2493x over previous
//
#include <hip/hip_runtime.h>
#include <hip/hip_bf16.h>

typedef __hip_bfloat16 bf16;
typedef __attribute__((ext_vector_type(8))) short short8;
typedef __attribute__((ext_vector_type(4))) float f32x4;

#define B_SZ 2
#define L_SEQ 512
#define VOCAB 512
#define D_MODEL 768
#define N_LAYERS 12
#define D_STATE 16
#define D_CONV 4
#define D_INNER 1536
#define DT_RANK 48
#define M_ROWS 1024
#define XDBL_C 80

// scan geometry: 8 d-lanes x 32 chunks of 16 steps
#define SDG 8
#define SNCH 32
#define SCL 16

#define LDPAD 40   // padded LDS row stride (shorts): 20 dwords -> conflict-free

__device__ __forceinline__ float silu_f(float x) {
    return x / (1.f + expf(-x));
}

__device__ __forceinline__ float b2f(bf16 x) { return __bfloat162float(x); }

__device__ __forceinline__ float bs2f(short s) {
    union { unsigned int u; float f; } cv;
    cv.u = ((unsigned int)(unsigned short)s) << 16;
    return cv.f;
}

__device__ __forceinline__ short f2bs(float x) {
    bf16 t = __float2bfloat16(x);
    return *reinterpret_cast<short*>(&t);
}

// fp32 -> bf16 bulk convert, 8 elems/thread
__global__ __launch_bounds__(256) void to_bf16_kernel(
    const float* __restrict__ src, bf16* __restrict__ dst, int n8)
{
    int i = blockIdx.x * 256 + threadIdx.x;
    if (i >= n8) return;
    const float4* s = (const float4*)src + (size_t)i * 2;
    float4 a = s[0], b = s[1];
    short8 v;
    v[0] = f2bs(a.x); v[1] = f2bs(a.y); v[2] = f2bs(a.z); v[3] = f2bs(a.w);
    v[4] = f2bs(b.x); v[5] = f2bs(b.y); v[6] = f2bs(b.z); v[7] = f2bs(b.w);
    *(short8*)((short*)dst + (size_t)i * 8) = v;
}

// 64x64x32 tile, 4 waves (2x2 of 32x32), padded LDS.
__global__ __launch_bounds__(256) void gemm64(
    const bf16* __restrict__ A, int lda,
    const bf16* __restrict__ W, int ldw,
    const float* __restrict__ bias, const float* addsrc,
    float* Cf, bf16* Cb, int M, int N, int K, int act)
{
    __shared__ short As[64 * LDPAD];
    __shared__ short Ws[64 * LDPAD];
    int t = threadIdx.x;
    int m0 = blockIdx.y * 64, n0 = blockIdx.x * 64;
    int wave = t >> 6, lane = t & 63;
    int wr = wave >> 1, wc = wave & 1;
    int lrow = lane & 15, lk = lane >> 4;
    int srow = t >> 2, scol = (t & 3) * 8;

    f32x4 acc[2][2] = {};

    for (int k0 = 0; k0 < K; k0 += 32) {
        int gk = k0 + scol;
        {
            short8 v = {};
            if (gk < K) v = *(const short8*)(A + (size_t)(m0 + srow) * lda + gk);
            *(short8*)(&As[srow * LDPAD + scol]) = v;
        }
        {
            int gn = n0 + srow;
            short8 v = {};
            if (gn < N && gk < K) v = *(const short8*)(W + (size_t)gn * ldw + gk);
            *(short8*)(&Ws[srow * LDPAD + scol]) = v;
        }
        __syncthreads();

        short8 af[2], bw[2];
#pragma unroll
        for (int i = 0; i < 2; i++) {
            af[i] = *(const short8*)(&As[(wr * 32 + i * 16 + lrow) * LDPAD + lk * 8]);
            bw[i] = *(const short8*)(&Ws[(wc * 32 + i * 16 + lrow) * LDPAD + lk * 8]);
        }
#pragma unroll
        for (int i = 0; i < 2; i++)
#pragma unroll
            for (int j = 0; j < 2; j++)
                acc[i][j] = __builtin_amdgcn_mfma_f32_16x16x32_bf16(af[i], bw[j], acc[i][j], 0, 0, 0);
        __syncthreads();
    }

#pragma unroll
    for (int i = 0; i < 2; i++)
#pragma unroll
        for (int j = 0; j < 2; j++) {
            int col = n0 + wc * 32 + j * 16 + lrow;
            if (col >= N) continue;
#pragma unroll
            for (int r = 0; r < 4; r++) {
                int row = m0 + wr * 32 + i * 16 + lk * 4 + r;
                float v = acc[i][j][r];
                if (bias) v += bias[col];
                if (addsrc) v += addsrc[(size_t)row * N + col];
                if (act == 1) v = (v > 20.f) ? v : log1pf(expf(v));
                if (Cf) Cf[(size_t)row * N + col] = v;
                if (Cb) Cb[(size_t)row * N + col] = __float2bfloat16(v);
            }
        }
}

// 128x128x32 tile, 4 waves (2x2 of 64x64), padded LDS (40 KB).
__global__ __launch_bounds__(256) void gemm128(
    const bf16* __restrict__ A, int lda,
    const bf16* __restrict__ W, int ldw,
    const float* __restrict__ bias, const float* addsrc,
    float* Cf, bf16* Cb, int M, int N, int K, int act)
{
    __shared__ short As[128 * LDPAD];
    __shared__ short Ws[128 * LDPAD];
    int t = threadIdx.x;
    int m0 = blockIdx.y * 128, n0 = blockIdx.x * 128;
    int wave = t >> 6, lane = t & 63;
    int wr = wave >> 1, wc = wave & 1;
    int lrow = lane & 15, lk = lane >> 4;
    int srow = t >> 2, scol = (t & 3) * 8;

    f32x4 acc[4][4] = {};

    for (int k0 = 0; k0 < K; k0 += 32) {
        int gk = k0 + scol;
#pragma unroll
        for (int p = 0; p < 2; p++) {
            int r = srow + p * 64;
            short8 v = {};
            if (gk < K) v = *(const short8*)(A + (size_t)(m0 + r) * lda + gk);
            *(short8*)(&As[r * LDPAD + scol]) = v;
        }
#pragma unroll
        for (int p = 0; p < 2; p++) {
            int r = srow + p * 64;
            int gn = n0 + r;
            short8 v = {};
            if (gn < N && gk < K) v = *(const short8*)(W + (size_t)gn * ldw + gk);
            *(short8*)(&Ws[r * LDPAD + scol]) = v;
        }
        __syncthreads();

        short8 af[4], bw[4];
#pragma unroll
        for (int i = 0; i < 4; i++) {
            af[i] = *(const short8*)(&As[(wr * 64 + i * 16 + lrow) * LDPAD + lk * 8]);
            bw[i] = *(const short8*)(&Ws[(wc * 64 + i * 16 + lrow) * LDPAD + lk * 8]);
        }
#pragma unroll
        for (int i = 0; i < 4; i++)
#pragma unroll
            for (int j = 0; j < 4; j++)
                acc[i][j] = __builtin_amdgcn_mfma_f32_16x16x32_bf16(af[i], bw[j], acc[i][j], 0, 0, 0);
        __syncthreads();
    }

#pragma unroll
    for (int i = 0; i < 4; i++)
#pragma unroll
        for (int j = 0; j < 4; j++) {
            int col = n0 + wc * 64 + j * 16 + lrow;
            if (col >= N) continue;
#pragma unroll
            for (int r = 0; r < 4; r++) {
                int row = m0 + wr * 64 + i * 16 + lk * 4 + r;
                float v = acc[i][j][r];
                if (bias) v += bias[col];
                if (addsrc) v += addsrc[(size_t)row * N + col];
                if (act == 1) v = (v > 20.f) ? v : log1pf(expf(v));
                if (Cf) Cf[(size_t)row * N + col] = v;
                if (Cb) Cb[(size_t)row * N + col] = __float2bfloat16(v);
            }
        }
}

// xp-proj as a dot-product kernel: out[m][n] = sum_k u[m][k] * W[n][k]
// one thread per output element; W (245 KB) is L2-resident.
__global__ __launch_bounds__(256) void xp_dot_kernel(
    const bf16* __restrict__ u, const bf16* __restrict__ W,
    bf16* __restrict__ xdbl)
{
    int idx = blockIdx.x * 256 + threadIdx.x;
    if (idx >= M_ROWS * XDBL_C) return;
    int n = idx % XDBL_C, m = idx / XDBL_C;
    const short8* ur = (const short8*)(u + (size_t)m * D_INNER);
    const short8* wr = (const short8*)(W + (size_t)n * D_INNER);
    float acc = 0.f;
    for (int k8 = 0; k8 < D_INNER / 8; k8++) {
        short8 a = ur[k8], b = wr[k8];
#pragma unroll
        for (int q = 0; q < 8; q++)
            acc += bs2f(a[q]) * bs2f(b[q]);
    }
    xdbl[idx] = __float2bfloat16(acc);
}

__global__ __launch_bounds__(256) void embed_kernel(
    const float* __restrict__ emb, const int* __restrict__ ids,
    float* __restrict__ x, bf16* __restrict__ xb)
{
    int idx = blockIdx.x * 256 + threadIdx.x;
    if (idx >= M_ROWS * D_MODEL) return;
    int m = idx / D_MODEL, k = idx % D_MODEL;
    float v = emb[(size_t)ids[m] * D_MODEL + k];
    x[idx] = v;
    xb[idx] = __float2bfloat16(v);
}

// vectorized conv+silu: 8 channels per thread
__global__ __launch_bounds__(256) void conv_silu_kernel(
    const bf16* __restrict__ xr, const float* __restrict__ w,
    const float* __restrict__ bias, bf16* __restrict__ u)
{
    int idx = blockIdx.x * 256 + threadIdx.x;
    if (idx >= M_ROWS * (D_INNER / 8)) return;
    int d8 = idx % (D_INNER / 8), m = idx / (D_INNER / 8);
    int d = d8 * 8;
    int l = m % L_SEQ;
    float acc[8];
#pragma unroll
    for (int q = 0; q < 8; q++) acc[q] = bias[d + q];
#pragma unroll
    for (int j = 0; j < D_CONV; j++) {
        int ls = l - (D_CONV - 1) + j;
        if (ls < 0) continue;
        short8 v = *(const short8*)(xr + (size_t)(m - (D_CONV - 1) + j) * (2 * D_INNER) + d);
#pragma unroll
        for (int q = 0; q < 8; q++)
            acc[q] += w[(d + q) * D_CONV + j] * bs2f(v[q]);
    }
    short8 sv;
#pragma unroll
    for (int q = 0; q < 8; q++) sv[q] = f2bs(silu_f(acc[q]));
    *(short8*)(u + (size_t)m * D_INNER + d) = sv;
}

// Chunked parallel scan, d-per-lane layout.
__global__ __launch_bounds__(256) void scan_chunked(
    const bf16* __restrict__ delta, const bf16* __restrict__ u,
    const bf16* __restrict__ xdbl, bf16* xrg,
    const float* __restrict__ A_log, const float* __restrict__ Dp)
{
    int t = threadIdx.x;
    int dl_ = t & (SDG - 1);
    int c   = t >> 3;
    int bg  = blockIdx.x;
    int b   = bg / (D_INNER / SDG);
    int dg  = bg % (D_INNER / SDG);
    int d   = dg * SDG + dl_;

    __shared__ float Pl[SNCH][SDG][17];
    __shared__ float Ql[SNCH][SDG][17];

    float An[D_STATE], h[D_STATE], Pp[D_STATE];
#pragma unroll
    for (int n = 0; n < D_STATE; n++) {
        An[n] = -expf(A_log[d * D_STATE + n]);
        h[n] = 0.f;
        Pp[n] = 1.f;
    }

    int m0 = b * L_SEQ + c * SCL;

    for (int i = 0; i < SCL; i++) {
        size_t m = m0 + i;
        float dlv = b2f(delta[m * D_INNER + d]);
        float uvv = b2f(u[m * D_INNER + d]);
        float duv = dlv * uvv;
        const short8* brow = (const short8*)((const short*)xdbl + m * XDBL_C + DT_RANK);
        short8 b0 = brow[0], b1 = brow[1];
#pragma unroll
        for (int n = 0; n < D_STATE; n++) {
            float a = expf(dlv * An[n]);
            Pp[n] *= a;
            float Bn = bs2f(n < 8 ? b0[n] : b1[n - 8]);
            h[n] = a * h[n] + duv * Bn;
        }
    }
#pragma unroll
    for (int n = 0; n < D_STATE; n++) {
        Pl[c][dl_][n] = Pp[n];
        Ql[c][dl_][n] = h[n];
    }
    __syncthreads();

    if (t < SDG * D_STATE) {
        int dd = t & (SDG - 1);
        int nn = t >> 3;
        float h0 = 0.f;
        for (int cc = 0; cc < SNCH; cc++) {
            float p = Pl[cc][dd][nn];
            float q = Ql[cc][dd][nn];
            Pl[cc][dd][nn] = h0;
            h0 = p * h0 + q;
        }
    }
    __syncthreads();

    float Dv = Dp[d];
#pragma unroll
    for (int n = 0; n < D_STATE; n++) h[n] = Pl[c][dl_][n];
    for (int i = 0; i < SCL; i++) {
        size_t m = m0 + i;
        float dlv = b2f(delta[m * D_INNER + d]);
        float uvv = b2f(u[m * D_INNER + d]);
        float duv = dlv * uvv;
        const short8* brow = (const short8*)((const short*)xdbl + m * XDBL_C + DT_RANK);
        short8 b0 = brow[0], b1 = brow[1];
        short8 c0 = brow[2], c1 = brow[3];
        float y = 0.f;
#pragma unroll
        for (int n = 0; n < D_STATE; n++) {
            float a = expf(dlv * An[n]);
            float Bn = bs2f(n < 8 ? b0[n] : b1[n - 8]);
            float Cn = bs2f(n < 8 ? c0[n] : c1[n - 8]);
            h[n] = a * h[n] + duv * Bn;
            y += h[n] * Cn;
        }
        y += uvv * Dv;
        float r = b2f(xrg[m * (2 * D_INNER) + D_INNER + d]);
        xrg[m * (2 * D_INNER) + d] = __float2bfloat16(y * silu_f(r));
    }
}

__global__ __launch_bounds__(256) void ln_kernel(
    const float* __restrict__ x, const float* __restrict__ gam,
    const float* __restrict__ bet, float* __restrict__ hidden_f32,
    bf16* __restrict__ hidden_bf)
{
    int row = blockIdx.x;
    const float* xr = x + (size_t)row * D_MODEL;
    float s = 0.f, s2 = 0.f;
    for (int i = threadIdx.x; i < D_MODEL; i += 256) {
        float v = xr[i];
        s += v; s2 += v * v;
    }
    __shared__ float red[18];
#pragma unroll
    for (int off = 32; off; off >>= 1) {
        s += __shfl_down(s, off);
        s2 += __shfl_down(s2, off);
    }
    int wid = threadIdx.x / 64, lane = threadIdx.x % 64;
    if (lane == 0) { red[wid * 2] = s; red[wid * 2 + 1] = s2; }
    __syncthreads();
    if (threadIdx.x == 0) {
        float ts = 0.f, ts2 = 0.f;
        for (int w = 0; w < 4; w++) { ts += red[w * 2]; ts2 += red[w * 2 + 1]; }
        red[16] = ts; red[17] = ts2;
    }
    __syncthreads();
    float mean = red[16] / D_MODEL;
    float var = red[17] / D_MODEL - mean * mean;
    float inv = rsqrtf(var + 1e-5f);
    for (int i = threadIdx.x; i < D_MODEL; i += 256) {
        float v = (xr[i] - mean) * inv * gam[i] + bet[i];
        hidden_f32[(size_t)row * D_MODEL + i] = v;
        hidden_bf[(size_t)row * D_MODEL + i] = __float2bfloat16(v);
    }
}

extern "C" void kernel_launch(void* const* d_in, const int* in_sizes, int n_in,
                              void* d_out, int out_size, void* d_ws, size_t ws_size,
                              hipStream_t stream) {
    const float* emb    = (const float*)d_in[0];
    const float* in_w   = (const float*)d_in[1];
    const float* conv_w = (const float*)d_in[2];
    const float* conv_b = (const float*)d_in[3];
    const float* xp_w   = (const float*)d_in[4];
    const float* dt_w   = (const float*)d_in[5];
    const float* dt_b   = (const float*)d_in[6];
    const float* A_log  = (const float*)d_in[7];
    const float* Dp     = (const float*)d_in[8];
    const float* out_w  = (const float*)d_in[9];
    const float* ln_g   = (const float*)d_in[10];
    const float* ln_b   = (const float*)d_in[11];
    const float* head_w = (const float*)d_in[12];
    const float* head_b = (const float*)d_in[13];
    const int*   ids    = (const int*)d_in[14];

    float* out_logits = (float*)d_out;
    float* out_hidden = (float*)d_out + (size_t)M_ROWS * VOCAB;

    char* base = (char*)d_ws;
    float* x       = (float*)(base);                        // 3,145,728 B
    bf16*  xb      = (bf16*) (base + 3145728);              // 1,572,864
    bf16*  xr      = (bf16*) (base + 4718592);              // 6,291,456
    bf16*  R       = (bf16*) (base + 11010048);             // 3,145,728
    bf16*  dlt     = (bf16*) (base + 14155776);             // 3,145,728
    bf16*  xdbl    = (bf16*) (base + 17301504);             //   163,840
    bf16*  hidb    = (bf16*) (base + 17465344);             // 1,572,864
    bf16*  in_wb   = (bf16*) (base + 19038208);             // 56,623,104
    bf16*  xp_wb   = (bf16*) (base + 75661312);             //  2,949,120
    bf16*  dt_wb   = (bf16*) (base + 78610432);             //  1,769,472
    bf16*  out_wb  = (bf16*) (base + 80379904);             // 28,311,552
    bf16*  head_wb = (bf16*) (base + 108691456);            //    786,432

    // weight conversion (per call; ~45 M elems)
    {
        struct { const float* s; bf16* d; int n; } cv[5] = {
            { in_w,   in_wb,   N_LAYERS * 2 * D_INNER * D_MODEL },
            { xp_w,   xp_wb,   N_LAYERS * XDBL_C * D_INNER },
            { dt_w,   dt_wb,   N_LAYERS * D_INNER * DT_RANK },
            { out_w,  out_wb,  N_LAYERS * D_MODEL * D_INNER },
            { head_w, head_wb, VOCAB * D_MODEL },
        };
        for (int i = 0; i < 5; i++) {
            int n8 = cv[i].n / 8;
            to_bf16_kernel<<<(n8 + 255) / 256, 256, 0, stream>>>(cv[i].s, cv[i].d, n8);
        }
    }

    embed_kernel<<<(M_ROWS * D_MODEL + 255) / 256, 256, 0, stream>>>(emb, ids, x, xb);

    for (int i = 0; i < N_LAYERS; i++) {
        const bf16*  in_wb_i  = in_wb  + (size_t)i * 2 * D_INNER * D_MODEL;
        const float* conv_w_i = conv_w + (size_t)i * D_INNER * D_CONV;
        const float* conv_b_i = conv_b + (size_t)i * D_INNER;
        const bf16*  xp_wb_i  = xp_wb  + (size_t)i * XDBL_C * D_INNER;
        const bf16*  dt_wb_i  = dt_wb  + (size_t)i * D_INNER * DT_RANK;
        const float* dt_b_i   = dt_b   + (size_t)i * D_INNER;
        const float* A_log_i  = A_log  + (size_t)i * D_INNER * D_STATE;
        const float* Dp_i     = Dp     + (size_t)i * D_INNER;
        const bf16*  out_wb_i = out_wb + (size_t)i * D_MODEL * D_INNER;

        // xr = xb @ in_w^T  [1024, 3072]  (192 blocks, 128^2 tile)
        gemm128<<<dim3(2 * D_INNER / 128, M_ROWS / 128), 256, 0, stream>>>(
            xb, D_MODEL, in_wb_i, D_MODEL, nullptr, nullptr, nullptr, xr,
            M_ROWS, 2 * D_INNER, D_MODEL, 0);

        // R = u = silu(conv(xr[:, :1536]) + conv_b)
        conv_silu_kernel<<<(M_ROWS * (D_INNER / 8) + 255) / 256, 256, 0, stream>>>(
            xr, conv_w_i, conv_b_i, R);

        // xdbl = R @ xp_w^T  [1024, 80]  (320 blocks, dot-product)
        xp_dot_kernel<<<(M_ROWS * XDBL_C + 255) / 256, 256, 0, stream>>>(
            R, xp_wb_i, xdbl);

        // dlt = softplus(xdbl[:, :48] @ dt_w^T + dt_b)  [1024, 1536]  (384 blocks)
        gemm64<<<dim3(D_INNER / 64, M_ROWS / 64), 256, 0, stream>>>(
            xdbl, XDBL_C, dt_wb_i, DT_RANK, dt_b_i, nullptr, nullptr, dlt,
            M_ROWS, D_INNER, DT_RANK, 1);

        // scan + gate fused; g -> xr[:, 0:1536]
        scan_chunked<<<B_SZ * (D_INNER / SDG), 256, 0, stream>>>(
            dlt, R, xdbl, xr, A_log_i, Dp_i);

        // x = g @ out_w^T + x ; xb = bf16(x)  (192 blocks)
        gemm64<<<dim3(D_MODEL / 64, M_ROWS / 64), 256, 0, stream>>>(
            xr, 2 * D_INNER, out_wb_i, D_INNER, nullptr, x, x, xb,
            M_ROWS, D_MODEL, D_INNER, 0);
    }

    ln_kernel<<<M_ROWS, 256, 0, stream>>>(x, ln_g, ln_b, out_hidden, hidb);

    // logits  (128 blocks)
    gemm64<<<dim3(VOCAB / 64, M_ROWS / 64), 256, 0, stream>>>(
        hidb, D_MODEL, head_wb, D_MODEL, head_b, nullptr, out_logits, nullptr,
        M_ROWS, VOCAB, D_MODEL, 0);
}

// Round 9
// 2086.447 us; speedup vs baseline: 1.5528x; 1.2429x over previous
//
#include <hip/hip_runtime.h>
#include <hip/hip_bf16.h>

typedef __hip_bfloat16 bf16;
typedef __attribute__((ext_vector_type(8))) short short8;
typedef __attribute__((ext_vector_type(4))) float f32x4;

#define B_SZ 2
#define L_SEQ 512
#define VOCAB 512
#define D_MODEL 768
#define N_LAYERS 12
#define D_STATE 16
#define D_CONV 4
#define D_INNER 1536
#define DT_RANK 48
#define M_ROWS 1024
#define XDBL_C 80

#define SDG 8
#define SNCH 32
#define SCL 16

#define LDPAD 40   // padded LDS row stride (shorts) -> conflict-free ds_read_b128

__device__ __forceinline__ float silu_f(float x) {
    return x / (1.f + expf(-x));
}

__device__ __forceinline__ float b2f(bf16 x) { return __bfloat162float(x); }

__device__ __forceinline__ float bs2f(short s) {
    union { unsigned int u; float f; } cv;
    cv.u = ((unsigned int)(unsigned short)s) << 16;
    return cv.f;
}

__device__ __forceinline__ short f2bs(float x) {
    bf16 t = __float2bfloat16(x);
    return *reinterpret_cast<short*>(&t);
}

__global__ __launch_bounds__(256) void to_bf16_kernel(
    const float* __restrict__ src, bf16* __restrict__ dst, int n8)
{
    int i = blockIdx.x * 256 + threadIdx.x;
    if (i >= n8) return;
    const float4* s = (const float4*)src + (size_t)i * 2;
    float4 a = s[0], b = s[1];
    short8 v;
    v[0] = f2bs(a.x); v[1] = f2bs(a.y); v[2] = f2bs(a.z); v[3] = f2bs(a.w);
    v[4] = f2bs(b.x); v[5] = f2bs(b.y); v[6] = f2bs(b.z); v[7] = f2bs(b.w);
    *(short8*)((short*)dst + (size_t)i * 8) = v;
}

// 64x64x32 tile, 4 waves (2x2 of 32x32), padded LDS, register-prefetch dbuf.
// Split-K: if Cpart != null, blockIdx.z selects k-range [z*klen, min(+klen,K));
// raw fp32 partials go to Cpart + z*M*N. Else full K with bias/addsrc/act epilogue.
__global__ __launch_bounds__(256) void gemm64(
    const bf16* __restrict__ A, int lda,
    const bf16* __restrict__ W, int ldw,
    const float* __restrict__ bias, const float* addsrc,
    float* Cf, bf16* Cb, float* Cpart, int klen,
    int M, int N, int K, int act)
{
    __shared__ short As[64 * LDPAD];
    __shared__ short Ws[64 * LDPAD];
    int t = threadIdx.x;
    int m0 = blockIdx.y * 64, n0 = blockIdx.x * 64;
    int wave = t >> 6, lane = t & 63;
    int wr = wave >> 1, wc = wave & 1;
    int lrow = lane & 15, lk = lane >> 4;
    int srow = t >> 2, scol = (t & 3) * 8;

    int ks = 0, ke = K;
    if (Cpart) {
        ks = blockIdx.z * klen;
        ke = min(ks + klen, K);
        Cpart += (size_t)blockIdx.z * M * N;
    }

    const bf16* Arow = A + (size_t)(m0 + srow) * lda;
    const bf16* Wrow = W + (size_t)(n0 + srow) * ldw;
    bool wok = (n0 + srow) < N;

    f32x4 acc[2][2] = {};

    // prefetch first k-step
    short8 ra = {}, rw = {};
    {
        int gk = ks + scol;
        if (gk < ke) ra = *(const short8*)(Arow + gk);
        if (wok && gk < ke) rw = *(const short8*)(Wrow + gk);
    }

    for (int k0 = ks; k0 < ke; k0 += 32) {
        *(short8*)(&As[srow * LDPAD + scol]) = ra;
        *(short8*)(&Ws[srow * LDPAD + scol]) = rw;
        __syncthreads();

        int kn = k0 + 32;
        if (kn < ke) {
            int gk = kn + scol;
            short8 za = {}, zw = {};
            if (gk < ke) za = *(const short8*)(Arow + gk);
            if (wok && gk < ke) zw = *(const short8*)(Wrow + gk);
            ra = za; rw = zw;
        }

        short8 af[2], bw[2];
#pragma unroll
        for (int i = 0; i < 2; i++) {
            af[i] = *(const short8*)(&As[(wr * 32 + i * 16 + lrow) * LDPAD + lk * 8]);
            bw[i] = *(const short8*)(&Ws[(wc * 32 + i * 16 + lrow) * LDPAD + lk * 8]);
        }
#pragma unroll
        for (int i = 0; i < 2; i++)
#pragma unroll
            for (int j = 0; j < 2; j++)
                acc[i][j] = __builtin_amdgcn_mfma_f32_16x16x32_bf16(af[i], bw[j], acc[i][j], 0, 0, 0);
        __syncthreads();
    }

#pragma unroll
    for (int i = 0; i < 2; i++)
#pragma unroll
        for (int j = 0; j < 2; j++) {
            int col = n0 + wc * 32 + j * 16 + lrow;
            if (col >= N) continue;
#pragma unroll
            for (int r = 0; r < 4; r++) {
                int row = m0 + wr * 32 + i * 16 + lk * 4 + r;
                float v = acc[i][j][r];
                if (Cpart) {
                    Cpart[(size_t)row * N + col] = v;
                } else {
                    if (bias) v += bias[col];
                    if (addsrc) v += addsrc[(size_t)row * N + col];
                    if (act == 1) v = (v > 20.f) ? v : log1pf(expf(v));
                    if (Cf) Cf[(size_t)row * N + col] = v;
                    if (Cb) Cb[(size_t)row * N + col] = __float2bfloat16(v);
                }
            }
        }
}

// x += sum of 4 partials; xb = bf16(x). float4-vectorized.
__global__ __launch_bounds__(256) void reduce_out_kernel(
    const float* __restrict__ Cp, float* __restrict__ x, bf16* __restrict__ xb)
{
    const int n = M_ROWS * D_MODEL;
    int i = blockIdx.x * 256 + threadIdx.x;
    if (i >= n / 4) return;
    float4 s0 = ((const float4*)Cp)[i];
    float4 s1 = ((const float4*)(Cp + n))[i];
    float4 s2 = ((const float4*)(Cp + 2 * n))[i];
    float4 s3 = ((const float4*)(Cp + 3 * n))[i];
    float4 xv = ((float4*)x)[i];
    xv.x += s0.x + s1.x + s2.x + s3.x;
    xv.y += s0.y + s1.y + s2.y + s3.y;
    xv.z += s0.z + s1.z + s2.z + s3.z;
    xv.w += s0.w + s1.w + s2.w + s3.w;
    ((float4*)x)[i] = xv;
    short* xbs = (short*)xb + (size_t)i * 4;
    xbs[0] = f2bs(xv.x); xbs[1] = f2bs(xv.y); xbs[2] = f2bs(xv.z); xbs[3] = f2bs(xv.w);
}

// logits = sum of 2 partials + head_b
__global__ __launch_bounds__(256) void reduce_head_kernel(
    const float* __restrict__ Cp, const float* __restrict__ head_b,
    float* __restrict__ logits)
{
    const int n = M_ROWS * VOCAB;
    int i = blockIdx.x * 256 + threadIdx.x;
    if (i >= n / 4) return;
    float4 s0 = ((const float4*)Cp)[i];
    float4 s1 = ((const float4*)(Cp + n))[i];
    float4 bv = ((const float4*)head_b)[i % (VOCAB / 4)];
    float4 o;
    o.x = s0.x + s1.x + bv.x;
    o.y = s0.y + s1.y + bv.y;
    o.z = s0.z + s1.z + bv.z;
    o.w = s0.w + s1.w + bv.w;
    ((float4*)logits)[i] = o;
}

// xp-proj dot-product kernel
__global__ __launch_bounds__(256) void xp_dot_kernel(
    const bf16* __restrict__ u, const bf16* __restrict__ W,
    bf16* __restrict__ xdbl)
{
    int idx = blockIdx.x * 256 + threadIdx.x;
    if (idx >= M_ROWS * XDBL_C) return;
    int n = idx % XDBL_C, m = idx / XDBL_C;
    const short8* ur = (const short8*)(u + (size_t)m * D_INNER);
    const short8* wr = (const short8*)(W + (size_t)n * D_INNER);
    float acc = 0.f;
    for (int k8 = 0; k8 < D_INNER / 8; k8++) {
        short8 a = ur[k8], b = wr[k8];
#pragma unroll
        for (int q = 0; q < 8; q++)
            acc += bs2f(a[q]) * bs2f(b[q]);
    }
    xdbl[idx] = __float2bfloat16(acc);
}

__global__ __launch_bounds__(256) void embed_kernel(
    const float* __restrict__ emb, const int* __restrict__ ids,
    float* __restrict__ x, bf16* __restrict__ xb)
{
    int idx = blockIdx.x * 256 + threadIdx.x;
    if (idx >= M_ROWS * D_MODEL) return;
    int m = idx / D_MODEL, k = idx % D_MODEL;
    float v = emb[(size_t)ids[m] * D_MODEL + k];
    x[idx] = v;
    xb[idx] = __float2bfloat16(v);
}

__global__ __launch_bounds__(256) void conv_silu_kernel(
    const bf16* __restrict__ xr, const float* __restrict__ w,
    const float* __restrict__ bias, bf16* __restrict__ u)
{
    int idx = blockIdx.x * 256 + threadIdx.x;
    if (idx >= M_ROWS * (D_INNER / 8)) return;
    int d8 = idx % (D_INNER / 8), m = idx / (D_INNER / 8);
    int d = d8 * 8;
    int l = m % L_SEQ;
    float acc[8];
#pragma unroll
    for (int q = 0; q < 8; q++) acc[q] = bias[d + q];
#pragma unroll
    for (int j = 0; j < D_CONV; j++) {
        int ls = l - (D_CONV - 1) + j;
        if (ls < 0) continue;
        short8 v = *(const short8*)(xr + (size_t)(m - (D_CONV - 1) + j) * (2 * D_INNER) + d);
#pragma unroll
        for (int q = 0; q < 8; q++)
            acc[q] += w[(d + q) * D_CONV + j] * bs2f(v[q]);
    }
    short8 sv;
#pragma unroll
    for (int q = 0; q < 8; q++) sv[q] = f2bs(silu_f(acc[q]));
    *(short8*)(u + (size_t)m * D_INNER + d) = sv;
}

// Chunked parallel scan, d-per-lane layout.
__global__ __launch_bounds__(256) void scan_chunked(
    const bf16* __restrict__ delta, const bf16* __restrict__ u,
    const bf16* __restrict__ xdbl, bf16* xrg,
    const float* __restrict__ A_log, const float* __restrict__ Dp)
{
    int t = threadIdx.x;
    int dl_ = t & (SDG - 1);
    int c   = t >> 3;
    int bg  = blockIdx.x;
    int b   = bg / (D_INNER / SDG);
    int dg  = bg % (D_INNER / SDG);
    int d   = dg * SDG + dl_;

    __shared__ float Pl[SNCH][SDG][17];
    __shared__ float Ql[SNCH][SDG][17];

    float An[D_STATE], h[D_STATE], Pp[D_STATE];
#pragma unroll
    for (int n = 0; n < D_STATE; n++) {
        An[n] = -expf(A_log[d * D_STATE + n]);
        h[n] = 0.f;
        Pp[n] = 1.f;
    }

    int m0 = b * L_SEQ + c * SCL;

    for (int i = 0; i < SCL; i++) {
        size_t m = m0 + i;
        float dlv = b2f(delta[m * D_INNER + d]);
        float uvv = b2f(u[m * D_INNER + d]);
        float duv = dlv * uvv;
        const short8* brow = (const short8*)((const short*)xdbl + m * XDBL_C + DT_RANK);
        short8 b0 = brow[0], b1 = brow[1];
#pragma unroll
        for (int n = 0; n < D_STATE; n++) {
            float a = expf(dlv * An[n]);
            Pp[n] *= a;
            float Bn = bs2f(n < 8 ? b0[n] : b1[n - 8]);
            h[n] = a * h[n] + duv * Bn;
        }
    }
#pragma unroll
    for (int n = 0; n < D_STATE; n++) {
        Pl[c][dl_][n] = Pp[n];
        Ql[c][dl_][n] = h[n];
    }
    __syncthreads();

    if (t < SDG * D_STATE) {
        int dd = t & (SDG - 1);
        int nn = t >> 3;
        float h0 = 0.f;
        for (int cc = 0; cc < SNCH; cc++) {
            float p = Pl[cc][dd][nn];
            float q = Ql[cc][dd][nn];
            Pl[cc][dd][nn] = h0;
            h0 = p * h0 + q;
        }
    }
    __syncthreads();

    float Dv = Dp[d];
#pragma unroll
    for (int n = 0; n < D_STATE; n++) h[n] = Pl[c][dl_][n];
    for (int i = 0; i < SCL; i++) {
        size_t m = m0 + i;
        float dlv = b2f(delta[m * D_INNER + d]);
        float uvv = b2f(u[m * D_INNER + d]);
        float duv = dlv * uvv;
        const short8* brow = (const short8*)((const short*)xdbl + m * XDBL_C + DT_RANK);
        short8 b0 = brow[0], b1 = brow[1];
        short8 c0 = brow[2], c1 = brow[3];
        float y = 0.f;
#pragma unroll
        for (int n = 0; n < D_STATE; n++) {
            float a = expf(dlv * An[n]);
            float Bn = bs2f(n < 8 ? b0[n] : b1[n - 8]);
            float Cn = bs2f(n < 8 ? c0[n] : c1[n - 8]);
            h[n] = a * h[n] + duv * Bn;
            y += h[n] * Cn;
        }
        y += uvv * Dv;
        float r = b2f(xrg[m * (2 * D_INNER) + D_INNER + d]);
        xrg[m * (2 * D_INNER) + d] = __float2bfloat16(y * silu_f(r));
    }
}

__global__ __launch_bounds__(256) void ln_kernel(
    const float* __restrict__ x, const float* __restrict__ gam,
    const float* __restrict__ bet, float* __restrict__ hidden_f32,
    bf16* __restrict__ hidden_bf)
{
    int row = blockIdx.x;
    const float* xr = x + (size_t)row * D_MODEL;
    float s = 0.f, s2 = 0.f;
    for (int i = threadIdx.x; i < D_MODEL; i += 256) {
        float v = xr[i];
        s += v; s2 += v * v;
    }
    __shared__ float red[18];
#pragma unroll
    for (int off = 32; off; off >>= 1) {
        s += __shfl_down(s, off);
        s2 += __shfl_down(s2, off);
    }
    int wid = threadIdx.x / 64, lane = threadIdx.x % 64;
    if (lane == 0) { red[wid * 2] = s; red[wid * 2 + 1] = s2; }
    __syncthreads();
    if (threadIdx.x == 0) {
        float ts = 0.f, ts2 = 0.f;
        for (int w = 0; w < 4; w++) { ts += red[w * 2]; ts2 += red[w * 2 + 1]; }
        red[16] = ts; red[17] = ts2;
    }
    __syncthreads();
    float mean = red[16] / D_MODEL;
    float var = red[17] / D_MODEL - mean * mean;
    float inv = rsqrtf(var + 1e-5f);
    for (int i = threadIdx.x; i < D_MODEL; i += 256) {
        float v = (xr[i] - mean) * inv * gam[i] + bet[i];
        hidden_f32[(size_t)row * D_MODEL + i] = v;
        hidden_bf[(size_t)row * D_MODEL + i] = __float2bfloat16(v);
    }
}

extern "C" void kernel_launch(void* const* d_in, const int* in_sizes, int n_in,
                              void* d_out, int out_size, void* d_ws, size_t ws_size,
                              hipStream_t stream) {
    const float* emb    = (const float*)d_in[0];
    const float* in_w   = (const float*)d_in[1];
    const float* conv_w = (const float*)d_in[2];
    const float* conv_b = (const float*)d_in[3];
    const float* xp_w   = (const float*)d_in[4];
    const float* dt_w   = (const float*)d_in[5];
    const float* dt_b   = (const float*)d_in[6];
    const float* A_log  = (const float*)d_in[7];
    const float* Dp     = (const float*)d_in[8];
    const float* out_w  = (const float*)d_in[9];
    const float* ln_g   = (const float*)d_in[10];
    const float* ln_b   = (const float*)d_in[11];
    const float* head_w = (const float*)d_in[12];
    const float* head_b = (const float*)d_in[13];
    const int*   ids    = (const int*)d_in[14];

    float* out_logits = (float*)d_out;
    float* out_hidden = (float*)d_out + (size_t)M_ROWS * VOCAB;

    char* base = (char*)d_ws;
    float* x       = (float*)(base);                        // 3,145,728 B
    bf16*  xb      = (bf16*) (base + 3145728);              // 1,572,864
    bf16*  xr      = (bf16*) (base + 4718592);              // 6,291,456
    bf16*  R       = (bf16*) (base + 11010048);             // 3,145,728
    bf16*  dlt     = (bf16*) (base + 14155776);             // 3,145,728
    bf16*  xdbl    = (bf16*) (base + 17301504);             //   163,840
    bf16*  hidb    = (bf16*) (base + 17465344);             // 1,572,864
    bf16*  in_wb   = (bf16*) (base + 19038208);             // 56,623,104
    bf16*  xp_wb   = (bf16*) (base + 75661312);             //  2,949,120
    bf16*  dt_wb   = (bf16*) (base + 78610432);             //  1,769,472
    bf16*  out_wb  = (bf16*) (base + 80379904);             // 28,311,552
    bf16*  head_wb = (bf16*) (base + 108691456);            //    786,432
    float* Cp      = (float*)(base + 110264320);            // 12,582,912

    {
        struct { const float* s; bf16* d; int n; } cv[5] = {
            { in_w,   in_wb,   N_LAYERS * 2 * D_INNER * D_MODEL },
            { xp_w,   xp_wb,   N_LAYERS * XDBL_C * D_INNER },
            { dt_w,   dt_wb,   N_LAYERS * D_INNER * DT_RANK },
            { out_w,  out_wb,  N_LAYERS * D_MODEL * D_INNER },
            { head_w, head_wb, VOCAB * D_MODEL },
        };
        for (int i = 0; i < 5; i++) {
            int n8 = cv[i].n / 8;
            to_bf16_kernel<<<(n8 + 255) / 256, 256, 0, stream>>>(cv[i].s, cv[i].d, n8);
        }
    }

    embed_kernel<<<(M_ROWS * D_MODEL + 255) / 256, 256, 0, stream>>>(emb, ids, x, xb);

    for (int i = 0; i < N_LAYERS; i++) {
        const bf16*  in_wb_i  = in_wb  + (size_t)i * 2 * D_INNER * D_MODEL;
        const float* conv_w_i = conv_w + (size_t)i * D_INNER * D_CONV;
        const float* conv_b_i = conv_b + (size_t)i * D_INNER;
        const bf16*  xp_wb_i  = xp_wb  + (size_t)i * XDBL_C * D_INNER;
        const bf16*  dt_wb_i  = dt_wb  + (size_t)i * D_INNER * DT_RANK;
        const float* dt_b_i   = dt_b   + (size_t)i * D_INNER;
        const float* A_log_i  = A_log  + (size_t)i * D_INNER * D_STATE;
        const float* Dp_i     = Dp     + (size_t)i * D_INNER;
        const bf16*  out_wb_i = out_wb + (size_t)i * D_MODEL * D_INNER;

        // xr = xb @ in_w^T  [1024, 3072]  (768 blocks, prefetch)
        gemm64<<<dim3(2 * D_INNER / 64, M_ROWS / 64), 256, 0, stream>>>(
            xb, D_MODEL, in_wb_i, D_MODEL, nullptr, nullptr, nullptr, xr,
            nullptr, 0, M_ROWS, 2 * D_INNER, D_MODEL, 0);

        // R = u = silu(conv(xr[:, :1536]) + conv_b)
        conv_silu_kernel<<<(M_ROWS * (D_INNER / 8) + 255) / 256, 256, 0, stream>>>(
            xr, conv_w_i, conv_b_i, R);

        // xdbl = R @ xp_w^T  [1024, 80]  (320 blocks)
        xp_dot_kernel<<<(M_ROWS * XDBL_C + 255) / 256, 256, 0, stream>>>(
            R, xp_wb_i, xdbl);

        // dlt = softplus(xdbl[:, :48] @ dt_w^T + dt_b)  (384 blocks)
        gemm64<<<dim3(D_INNER / 64, M_ROWS / 64), 256, 0, stream>>>(
            xdbl, XDBL_C, dt_wb_i, DT_RANK, dt_b_i, nullptr, nullptr, dlt,
            nullptr, 0, M_ROWS, D_INNER, DT_RANK, 1);

        // scan + gate fused; g -> xr[:, 0:1536]
        scan_chunked<<<B_SZ * (D_INNER / SDG), 256, 0, stream>>>(
            dlt, R, xdbl, xr, A_log_i, Dp_i);

        // out-proj split-K x4: partials  (12 x 16 x 4 = 768 blocks)
        gemm64<<<dim3(D_MODEL / 64, M_ROWS / 64, 4), 256, 0, stream>>>(
            xr, 2 * D_INNER, out_wb_i, D_INNER, nullptr, nullptr, nullptr, nullptr,
            Cp, 384, M_ROWS, D_MODEL, D_INNER, 0);

        // x += sum(partials); xb = bf16(x)
        reduce_out_kernel<<<(M_ROWS * D_MODEL / 4 + 255) / 256, 256, 0, stream>>>(
            Cp, x, xb);
    }

    ln_kernel<<<M_ROWS, 256, 0, stream>>>(x, ln_g, ln_b, out_hidden, hidb);

    // head split-K x2: partials  (8 x 16 x 2 = 256 blocks)
    gemm64<<<dim3(VOCAB / 64, M_ROWS / 64, 2), 256, 0, stream>>>(
        hidb, D_MODEL, head_wb, D_MODEL, nullptr, nullptr, nullptr, nullptr,
        Cp, 384, M_ROWS, VOCAB, D_MODEL, 0);

    reduce_head_kernel<<<(M_ROWS * VOCAB / 4 + 255) / 256, 256, 0, stream>>>(
        Cp, head_b, out_logits);
}